// Round 9
// baseline (536.195 us; speedup 1.0000x reference)
//
#include <hip/hip_runtime.h>

#define HC 128      // hidden / latent channels
#define FIN 64
#define DHID 1024
#define ZK 134      // LAT + 6
#define ZKP 160     // ZK padded to multiple of 32 for MFMA head
#define NSCAT 4     // dst-range partitions for scatter write locality

typedef __attribute__((ext_vector_type(8))) short short8;
typedef __attribute__((ext_vector_type(8))) __bf16 bf16x8;
typedef __attribute__((ext_vector_type(4))) float f32x4;
typedef __attribute__((ext_vector_type(8))) unsigned short u16x8;
typedef __attribute__((ext_vector_type(4))) unsigned short u16x4;

union FragU { short8 s; bf16x8 b; u16x8 u; };

__device__ inline unsigned short rne_bf16(float x) {
    union { float f; unsigned u; } v; v.f = x;
    unsigned u = v.u;
    unsigned r = (u + 0x7fffu + ((u >> 16) & 1u)) >> 16;
    return (unsigned short)r;
}
__device__ inline float bf16_to_f(unsigned short h) {
    union { unsigned u; float f; } v; v.u = ((unsigned)h) << 16;
    return v.f;
}

// ---------------------------------------------------------------- small utils
__global__ void k_deg_i(const int* __restrict__ dst, int* __restrict__ cnt, int E) {
    int i = blockIdx.x * blockDim.x + threadIdx.x;
    if (i < E) atomicAdd(&cnt[dst[i]], 1);
}

// x fp32 -> bf16 table
__global__ void k_xtobf(const float* __restrict__ x, unsigned short* __restrict__ xb, int n4) {
    int i = blockIdx.x * blockDim.x + threadIdx.x;
    if (i >= n4) return;
    float4 v = ((const float4*)x)[i];
    u16x4 o;
    o[0] = rne_bf16(v.x); o[1] = rne_bf16(v.y);
    o[2] = rne_bf16(v.z); o[3] = rne_bf16(v.w);
    ((u16x4*)xb)[i] = o;
}

// ---------------------------------------------------------------- scan (CSR row offsets) + dinv
__global__ void k_scan1(const int* __restrict__ cnt, int* __restrict__ part,
                        int* __restrict__ bsum, float* __restrict__ dinv, int N) {
    __shared__ int sh[256];
    int t = threadIdx.x, i = blockIdx.x * 256 + t;
    int v = (i < N) ? cnt[i] : 0;
    if (i < N) dinv[i] = rsqrtf((float)v + 1.0f);
    sh[t] = v; __syncthreads();
    #pragma unroll
    for (int off = 1; off < 256; off <<= 1) {
        int tv = (t >= off) ? sh[t - off] : 0;
        __syncthreads();
        sh[t] += tv;
        __syncthreads();
    }
    if (i < N) part[i] = sh[t] - v;
    if (t == 255) bsum[blockIdx.x] = sh[255];
}

__global__ void k_scan2(int* __restrict__ bsum, int nb) {
    __shared__ int sh[256];
    int t = threadIdx.x;
    int v = (t < nb) ? bsum[t] : 0;
    sh[t] = v; __syncthreads();
    #pragma unroll
    for (int off = 1; off < 256; off <<= 1) {
        int tv = (t >= off) ? sh[t - off] : 0;
        __syncthreads();
        sh[t] += tv;
        __syncthreads();
    }
    if (t < nb) bsum[t] = sh[t] - v;
}

// row_start AND cur both get the exclusive-scan value (cur is the live cursor)
__global__ void k_scan3(const int* __restrict__ part, const int* __restrict__ bsum,
                        int* __restrict__ row_start, int* __restrict__ cur, int N) {
    int i = blockIdx.x * 256 + threadIdx.x;
    if (i < N) { int v = part[i] + bsum[blockIdx.x]; row_start[i] = v; cur[i] = v; }
}

// dst-range-partitioned scatter: pos comes straight from the atomic (cur pre-seeded
// with row_start). blockIdx.y selects the dst range -> csr/cur writes stay L2-local.
__global__ void k_scatter2(const int* __restrict__ src, const int* __restrict__ dst,
                           const float* __restrict__ dinv,
                           int* __restrict__ cur, int2* __restrict__ csr,
                           int E, int rangeSize) {
    int e = blockIdx.x * blockDim.x + threadIdx.x;
    if (e >= E) return;
    int d = dst[e];
    int lo = blockIdx.y * rangeSize;
    if (d < lo || d >= lo + rangeSize) return;
    int s = src[e];
    int pos = atomicAdd(&cur[d], 1);
    int2 pk; pk.x = s; pk.y = __float_as_int(dinv[s] * dinv[d]);
    csr[pos] = pk;
}

// ---------------------------------------------------------------- gather (bf16 table -> bf16 out, fp32 accum)
template <int RF> struct BVec;
template <> struct BVec<64>  { using T = u16x4; static const int VPL = 4; };
template <> struct BVec<128> { using T = u16x8; static const int VPL = 8; };

// quarter-wave (16 lanes) per node; lane reads RF/16 features as one vector
template <int RF>
__global__ __launch_bounds__(256) void k_gather2b(const unsigned short* __restrict__ T,
                                                  const int2* __restrict__ csr,
                                                  const int* __restrict__ row_start,
                                                  const int* __restrict__ cnt,
                                                  const float* __restrict__ dinv,
                                                  unsigned short* __restrict__ agg, int N) {
    using vec = typename BVec<RF>::T;
    constexpr int VPL = BVec<RF>::VPL;
    int tid = threadIdx.x;
    int node = blockIdx.x * 16 + (tid >> 4);
    int q = tid & 15;
    if (node >= N) return;
    int beg = row_start[node];
    int end = beg + cnt[node];
    float d = dinv[node];
    vec sv = ((const vec*)(T + (size_t)node * RF))[q];
    float acc[VPL];
    #pragma unroll
    for (int i = 0; i < VPL; ++i) acc[i] = bf16_to_f(sv[i]) * d * d;
    int j = beg;
    for (; j + 8 <= end; j += 8) {
        int2 e[8];
        #pragma unroll
        for (int u = 0; u < 8; ++u) e[u] = csr[j + u];
        vec v[8];
        #pragma unroll
        for (int u = 0; u < 8; ++u) v[u] = ((const vec*)(T + (size_t)e[u].x * RF))[q];
        #pragma unroll
        for (int u = 0; u < 8; ++u) {
            float nn = __int_as_float(e[u].y);
            #pragma unroll
            for (int i = 0; i < VPL; ++i) acc[i] += bf16_to_f(v[u][i]) * nn;
        }
    }
    for (; j + 2 <= end; j += 2) {
        int2 e0 = csr[j], e1 = csr[j + 1];
        vec v0 = ((const vec*)(T + (size_t)e0.x * RF))[q];
        vec v1 = ((const vec*)(T + (size_t)e1.x * RF))[q];
        float n0 = __int_as_float(e0.y), n1 = __int_as_float(e1.y);
        #pragma unroll
        for (int i = 0; i < VPL; ++i)
            acc[i] += bf16_to_f(v0[i]) * n0 + bf16_to_f(v1[i]) * n1;
    }
    if (j < end) {
        int2 e0 = csr[j];
        vec v0 = ((const vec*)(T + (size_t)e0.x * RF))[q];
        float n0 = __int_as_float(e0.y);
        #pragma unroll
        for (int i = 0; i < VPL; ++i) acc[i] += bf16_to_f(v0[i]) * n0;
    }
    vec o;
    #pragma unroll
    for (int i = 0; i < VPL; ++i) o[i] = rne_bf16(acc[i]);
    ((vec*)(agg + (size_t)node * RF))[q] = o;
}

// ---------------------------------------------------------------- batchnorm stats (vectorized u16x8)
__global__ __launch_bounds__(256) void k_bn_reduce2(const unsigned short* __restrict__ x,
                                                    float* __restrict__ stat, int N) {
    int cg = threadIdx.x & 15;        // col group: cols cg*8 .. cg*8+7
    int rr = threadIdx.x >> 4;        // 0..15
    int rpb = (N + gridDim.x - 1) / gridDim.x;
    int r0 = blockIdx.x * rpb;
    int r1 = min(N, r0 + rpb);
    float s[8] = {}, ss[8] = {};
    for (int r = r0 + rr; r < r1; r += 16) {
        u16x8 v = *(const u16x8*)(x + (size_t)r * HC + cg * 8);
        #pragma unroll
        for (int j = 0; j < 8; ++j) { float f = bf16_to_f(v[j]); s[j] += f; ss[j] += f * f; }
    }
    __shared__ float shs[16][16][8];
    __shared__ float shq[16][16][8];
    #pragma unroll
    for (int j = 0; j < 8; ++j) { shs[rr][cg][j] = s[j]; shq[rr][cg][j] = ss[j]; }
    __syncthreads();
    #pragma unroll
    for (int off = 8; off > 0; off >>= 1) {
        if (rr < off) {
            #pragma unroll
            for (int j = 0; j < 8; ++j) {
                shs[rr][cg][j] += shs[rr + off][cg][j];
                shq[rr][cg][j] += shq[rr + off][cg][j];
            }
        }
        __syncthreads();
    }
    if (rr == 0) {
        #pragma unroll
        for (int j = 0; j < 8; ++j) {
            atomicAdd(&stat[cg * 8 + j],      shs[0][cg][j]);
            atomicAdd(&stat[HC + cg * 8 + j], shq[0][cg][j]);
        }
    }
}

// in-place BN+ReLU on bf16 table; scale/shift recomputed inline from stats (cheap)
__global__ void k_bn_apply3(unsigned short* __restrict__ t, const float* __restrict__ stat,
                            const float* __restrict__ gam, const float* __restrict__ bet,
                            float invN, int total8) {
    int i = blockIdx.x * blockDim.x + threadIdx.x;
    if (i >= total8) return;
    int k0 = (i * 8) & (HC - 1);
    u16x8 v = ((const u16x8*)t)[i];
    u16x8 o;
    #pragma unroll
    for (int j = 0; j < 8; ++j) {
        int k = k0 + j;
        float m = stat[k] * invN;
        float var = stat[HC + k] * invN - m * m;
        float istd = rsqrtf(var + 1e-5f);
        float sc = gam[k] * istd;
        float sh = bet[k] - m * sc;
        o[j] = rne_bf16(fmaxf(bf16_to_f(v[j]) * sc + sh, 0.f));
    }
    ((u16x8*)t)[i] = o;
}

// ---------------------------------------------------------------- pooling (BN3 inline, bf16 input)
__global__ void k_pool(const unsigned short* __restrict__ h, const int* __restrict__ batch,
                       const float* __restrict__ stat, const float* __restrict__ gam,
                       const float* __restrict__ bet, float invN,
                       float* __restrict__ pooled, float* __restrict__ cnt, int N) {
    int t = threadIdx.x;  // 0..127
    float m = stat[t] * invN;
    float var = stat[HC + t] * invN - m * m;
    float istd = rsqrtf(var + 1e-5f);
    float scv = gam[t] * istd;
    float shv = bet[t] - m * scv;
    int rpb = (N + gridDim.x - 1) / gridDim.x;
    int r0 = blockIdx.x * rpb;
    int r1 = min(N, r0 + rpb);
    if (r0 >= r1) return;
    int curb = batch[r0];
    float acc = 0.f; float c = 0.f;
    for (int r = r0; r < r1; ++r) {
        int b = batch[r];
        if (b != curb) {
            atomicAdd(&pooled[curb * HC + t], acc);
            if (t == 0) atomicAdd(&cnt[curb], c);
            curb = b; acc = 0.f; c = 0.f;
        }
        acc += bf16_to_f(h[(size_t)r * HC + t]) * scv + shv;
        c += 1.f;
    }
    atomicAdd(&pooled[curb * HC + t], acc);
    if (t == 0) atomicAdd(&cnt[curb], c);
}

// build z padded to ZKP cols (pad = 0)
__global__ void k_build_z(const float* __restrict__ pooled, const float* __restrict__ cnt,
                          const float* __restrict__ origin, const float* __restrict__ dir,
                          float* __restrict__ z, int G) {
    int g = blockIdx.x;
    int t = threadIdx.x;
    if (t >= ZKP) return;
    float v = 0.f;
    if (t < HC) {
        float c = fmaxf(cnt[g], 1.0f);
        v = pooled[g * HC + t] / c;
    } else if (t < HC + 3) {
        v = origin[g * 3 + (t - HC)];
    } else if (t < HC + 6) {
        v = dir[g * 3 + (t - HC - 3)];
    }
    z[g * ZKP + t] = v;
}

// ---------------------------------------------------------------- W prep (all 3 GCN weights): fp32 [K][128] -> bf16 hi/lo transposed [128][K]
__global__ void k_wprep_all(const float* __restrict__ W1, const float* __restrict__ W2,
                            const float* __restrict__ W3,
                            unsigned short* __restrict__ w1h, unsigned short* __restrict__ w1l,
                            unsigned short* __restrict__ w2h, unsigned short* __restrict__ w2l,
                            unsigned short* __restrict__ w3h, unsigned short* __restrict__ w3l) {
    int i = blockIdx.x * blockDim.x + threadIdx.x;
    const float* W; unsigned short *th, *tl; int K, idx;
    if (i < FIN * HC)           { W = W1; th = w1h; tl = w1l; K = FIN; idx = i; }
    else if (i < FIN*HC + HC*HC){ W = W2; th = w2h; tl = w2l; K = HC;  idx = i - FIN*HC; }
    else if (i < FIN*HC + 2*HC*HC){ W = W3; th = w3h; tl = w3l; K = HC; idx = i - FIN*HC - HC*HC; }
    else return;
    int k = idx >> 7, n = idx & (HC - 1);
    float w = W[idx];
    unsigned short h = rne_bf16(w);
    th[n * K + k] = h;
    tl[n * K + k] = rne_bf16(w - bf16_to_f(h));
}

// ---------------------------------------------------------------- W prep (head): fp32 [K][NC] -> bf16 hi/lo transposed [NC][KP]
__global__ __launch_bounds__(256) void k_wprep2(const float* __restrict__ W,
                                                unsigned short* __restrict__ th,
                                                unsigned short* __restrict__ tl,
                                                int K, int KP, int NC) {
    __shared__ float tile[32][33];
    int kt = blockIdx.x * 32, nt = blockIdx.y * 32;
    int tx = threadIdx.x & 31, ty0 = threadIdx.x >> 5;
    #pragma unroll
    for (int i = 0; i < 4; ++i) {
        int ty = ty0 + i * 8;
        int k = kt + ty;
        float v = (k < K) ? W[(size_t)k * NC + nt + tx] : 0.f;
        tile[ty][tx] = v;
    }
    __syncthreads();
    #pragma unroll
    for (int i = 0; i < 4; ++i) {
        int ty = ty0 + i * 8;
        int n = nt + ty;
        int k = kt + tx;
        float w = tile[tx][ty];
        unsigned short h = rne_bf16(w);
        th[(size_t)n * KP + k] = h;
        tl[(size_t)n * KP + k] = rne_bf16(w - bf16_to_f(h));
    }
}

// ---------------------------------------------------------------- MFMA node GEMM (pure bf16 A)
// C[M,128] = A[M,KK] @ W[KK,128]; A raw bf16 (BN pre-applied), W hi/lo split.
// 512 thr = 8 waves (2 row x 4 col); wave = 16 rows x 32 cols; 64 rows/block.
template <int KK>
__global__ __launch_bounds__(512) void gemm_node2(const unsigned short* __restrict__ A,
                                                  const unsigned short* __restrict__ wth,
                                                  const unsigned short* __restrict__ wtl,
                                                  unsigned short* __restrict__ C, int M) {
    constexpr int KS = KK / 32;
    int tid = threadIdx.x;
    int lane = tid & 63, wid = tid >> 6;
    int rw = wid & 1, cg = wid >> 1;          // rw 0/1, cg 0..3
    int l15 = lane & 15, l4 = lane >> 4;
    int cbase = cg * 32;

    FragU bh[2][KS], bl[2][KS];
    #pragma unroll
    for (int ct = 0; ct < 2; ++ct) {
        int n = cbase + ct * 16 + l15;
        #pragma unroll
        for (int ks = 0; ks < KS; ++ks) {
            int k = ks * 32 + l4 * 8;
            bh[ct][ks].s = *(const short8*)(wth + (size_t)n * KK + k);
            bl[ct][ks].s = *(const short8*)(wtl + (size_t)n * KK + k);
        }
    }

    #pragma unroll
    for (int rt = 0; rt < 2; ++rt) {
        int m0 = blockIdx.x * 64 + rt * 32 + rw * 16;
        if (m0 < M) {
            int arow = min(m0 + l15, M - 1);
            f32x4 zero = {0.f, 0.f, 0.f, 0.f};
            f32x4 acc[2] = {zero, zero};
            #pragma unroll
            for (int ks = 0; ks < KS; ++ks) {
                int k0 = ks * 32 + l4 * 8;
                FragU a;
                a.u = *(const u16x8*)(A + (size_t)arow * KK + k0);
                #pragma unroll
                for (int ct = 0; ct < 2; ++ct) {
                    acc[ct] = __builtin_amdgcn_mfma_f32_16x16x32_bf16(a.b, bh[ct][ks].b, acc[ct], 0, 0, 0);
                    acc[ct] = __builtin_amdgcn_mfma_f32_16x16x32_bf16(a.b, bl[ct][ks].b, acc[ct], 0, 0, 0);
                }
            }
            #pragma unroll
            for (int ct = 0; ct < 2; ++ct) {
                int col = cbase + ct * 16 + l15;
                #pragma unroll
                for (int r = 0; r < 4; ++r) {
                    int row = m0 + l4 * 4 + r;
                    if (row < M)
                        C[(size_t)row * HC + col] = rne_bf16(acc[ct][r]);
                }
            }
        }
    }
}

// ---------------------------------------------------------------- MFMA head GEMM, split-K
__global__ __launch_bounds__(256) void gemm_head_sk(const float* __restrict__ A,
                                                    const unsigned short* __restrict__ wth,
                                                    const unsigned short* __restrict__ wtl,
                                                    float* __restrict__ Cpart,
                                                    int M, int N, int K, int slice) {
    int tid = threadIdx.x;
    int lane = tid & 63, wid = tid >> 6;
    int rw = wid & 1, cw = wid >> 1;
    int l15 = lane & 15, l4 = lane >> 4;
    int m0 = blockIdx.y * 32 + rw * 16;
    int cb = blockIdx.x * 64 + cw * 32;
    int z = blockIdx.z;
    int kbeg = z * slice;
    int kend = min(K, kbeg + slice);
    if (m0 >= M) return;

    int arow = m0 + l15;
    f32x4 zero = {0.f, 0.f, 0.f, 0.f};
    f32x4 acc[2] = {zero, zero};

    for (int k0 = kbeg; k0 < kend; k0 += 32) {
        int ka = k0 + l4 * 8;
        const float4 p0 = *(const float4*)(A + (size_t)arow * K + ka);
        const float4 p1 = *(const float4*)(A + (size_t)arow * K + ka + 4);
        float av[8] = {p0.x, p0.y, p0.z, p0.w, p1.x, p1.y, p1.z, p1.w};
        FragU ah, al;
        #pragma unroll
        for (int i = 0; i < 8; ++i) {
            unsigned short h = rne_bf16(av[i]);
            ah.s[i] = (short)h;
            al.s[i] = (short)rne_bf16(av[i] - bf16_to_f(h));
        }
        #pragma unroll
        for (int ct = 0; ct < 2; ++ct) {
            int n = cb + ct * 16 + l15;
            FragU bh, bl;
            bh.s = *(const short8*)(wth + (size_t)n * K + ka);
            bl.s = *(const short8*)(wtl + (size_t)n * K + ka);
            acc[ct] = __builtin_amdgcn_mfma_f32_16x16x32_bf16(ah.b, bh.b, acc[ct], 0, 0, 0);
            acc[ct] = __builtin_amdgcn_mfma_f32_16x16x32_bf16(ah.b, bl.b, acc[ct], 0, 0, 0);
            acc[ct] = __builtin_amdgcn_mfma_f32_16x16x32_bf16(al.b, bh.b, acc[ct], 0, 0, 0);
        }
    }

    float* Cz = Cpart + (size_t)z * M * N;
    #pragma unroll
    for (int ct = 0; ct < 2; ++ct) {
        int col = cb + ct * 16 + l15;
        #pragma unroll
        for (int r = 0; r < 4; ++r) {
            int row = m0 + l4 * 4 + r;
            Cz[(size_t)row * N + col] = acc[ct][r];
        }
    }
}

// sum NZ partials + bias + relu; N power of two (DHID)
__global__ void k_reduce_br(const float* __restrict__ part, const float* __restrict__ bias,
                            float* __restrict__ C, int MN, int Nmask, int NZ) {
    int i = (blockIdx.x * blockDim.x + threadIdx.x) * 4;
    if (i >= MN) return;
    float4 acc = *(const float4*)(part + i);
    for (int zz = 1; zz < NZ; ++zz) {
        float4 p = *(const float4*)(part + (size_t)zz * MN + i);
        acc.x += p.x; acc.y += p.y; acc.z += p.z; acc.w += p.w;
    }
    int n = i & Nmask;
    acc.x += bias[n]; acc.y += bias[n + 1]; acc.z += bias[n + 2]; acc.w += bias[n + 3];
    acc.x = fmaxf(acc.x, 0.f); acc.y = fmaxf(acc.y, 0.f);
    acc.z = fmaxf(acc.z, 0.f); acc.w = fmaxf(acc.w, 0.f);
    *(float4*)(C + i) = acc;
}

// final [G,DH] @ [DH,3] + bout
__global__ void k_dense_out(const float* __restrict__ z, const float* __restrict__ W,
                            const float* __restrict__ b, float* __restrict__ out, int K) {
    int g = blockIdx.x;
    const float* zr = z + (size_t)g * K;
    float a0 = 0.f, a1 = 0.f, a2 = 0.f;
    for (int k = threadIdx.x; k < K; k += blockDim.x) {
        float zv = zr[k];
        a0 += zv * W[k * 3 + 0];
        a1 += zv * W[k * 3 + 1];
        a2 += zv * W[k * 3 + 2];
    }
    __shared__ float s[768];
    s[threadIdx.x] = a0; s[256 + threadIdx.x] = a1; s[512 + threadIdx.x] = a2;
    __syncthreads();
    for (int off = 128; off > 0; off >>= 1) {
        if ((int)threadIdx.x < off) {
            s[threadIdx.x]       += s[threadIdx.x + off];
            s[256 + threadIdx.x] += s[256 + threadIdx.x + off];
            s[512 + threadIdx.x] += s[512 + threadIdx.x + off];
        }
        __syncthreads();
    }
    if (threadIdx.x == 0) {
        out[g * 3 + 0] = s[0]   + b[0];
        out[g * 3 + 1] = s[256] + b[1];
        out[g * 3 + 2] = s[512] + b[2];
    }
}

// ---------------------------------------------------------------- launch
extern "C" void kernel_launch(void* const* d_in, const int* in_sizes, int n_in,
                              void* d_out, int out_size, void* d_ws, size_t ws_size,
                              hipStream_t stream) {
    const float* x         = (const float*)d_in[0];
    const float* origin    = (const float*)d_in[1];
    const float* direction = (const float*)d_in[2];
    const int*   eidx      = (const int*)d_in[3];
    const int*   batch     = (const int*)d_in[4];
    const float* W1 = (const float*)d_in[5];
    const float* W2 = (const float*)d_in[7];
    const float* W3 = (const float*)d_in[9];
    const float* g1 = (const float*)d_in[11]; const float* be1 = (const float*)d_in[12];
    const float* g2 = (const float*)d_in[13]; const float* be2 = (const float*)d_in[14];
    const float* g3 = (const float*)d_in[15]; const float* be3 = (const float*)d_in[16];
    const float* Wd0 = (const float*)d_in[17]; const float* bd0 = (const float*)d_in[18];
    const float* Wd1 = (const float*)d_in[19]; const float* bd1 = (const float*)d_in[20];
    const float* Wd2 = (const float*)d_in[21]; const float* bd2 = (const float*)d_in[22];
    const float* Wout = (const float*)d_in[23]; const float* bout = (const float*)d_in[24];
    float* out = (float*)d_out;

    const int N = in_sizes[4];
    const int E = in_sizes[3] / 2;
    const int G = in_sizes[1] / 3;
    const int* src = eidx;
    const int* dst = eidx + E;

    char* ws = (char*)d_ws;
    size_t off = 0;
    auto alloc = [&](size_t nbytes) -> void* {
        void* p = (void*)(ws + off);
        off += (nbytes + 255) & ~(size_t)255;
        return p;
    };
    // zero-init region (one memset): colstats | pooled | cntf | degcnt
    float* colstats = (float*)alloc(3 * 2 * HC * 4);
    float* pooled   = (float*)alloc((size_t)G * HC * 4);
    float* cntf     = (float*)alloc((size_t)G * 4);
    int*   degcnt   = (int*)alloc((size_t)N * 4);
    const size_t zeroBytes = 3 * 2 * HC * 4 + (size_t)G * HC * 4 + 1024 /*cntf pad*/ + (size_t)N * 4;

    float* dinv     = (float*)alloc((size_t)N * 4);
    int*   part     = (int*)alloc((size_t)N * 4);
    int*   bsum     = (int*)alloc(256 * 4);
    int*   row_start= (int*)alloc((size_t)N * 4);
    int*   cur      = (int*)alloc((size_t)N * 4);
    int2*  csr      = (int2*)alloc((size_t)E * 8);
    unsigned short* xb   = (unsigned short*)alloc((size_t)N * FIN * 2);
    unsigned short* aggx = (unsigned short*)alloc((size_t)N * FIN * 2);
    unsigned short* tabA = (unsigned short*)alloc((size_t)N * HC * 2);
    unsigned short* tabB = (unsigned short*)alloc((size_t)N * HC * 2);
    unsigned short* wt1h = (unsigned short*)alloc((size_t)FIN * HC * 2);
    unsigned short* wt1l = (unsigned short*)alloc((size_t)FIN * HC * 2);
    unsigned short* wt2h = (unsigned short*)alloc((size_t)HC * HC * 2);
    unsigned short* wt2l = (unsigned short*)alloc((size_t)HC * HC * 2);
    unsigned short* wt3h = (unsigned short*)alloc((size_t)HC * HC * 2);
    unsigned short* wt3l = (unsigned short*)alloc((size_t)HC * HC * 2);
    unsigned short* wd0h = (unsigned short*)alloc((size_t)DHID * ZKP * 2);
    unsigned short* wd0l = (unsigned short*)alloc((size_t)DHID * ZKP * 2);
    unsigned short* wd1h = (unsigned short*)alloc((size_t)DHID * DHID * 2);
    unsigned short* wd1l = (unsigned short*)alloc((size_t)DHID * DHID * 2);
    unsigned short* wd2h = (unsigned short*)alloc((size_t)DHID * DHID * 2);
    unsigned short* wd2l = (unsigned short*)alloc((size_t)DHID * DHID * 2);
    float* zbuf     = (float*)alloc((size_t)G * ZKP * 4);
    float* t0       = (float*)alloc((size_t)G * DHID * 4);
    float* t1       = (float*)alloc((size_t)G * DHID * 4);
    float* kpart    = (float*)alloc((size_t)8 * G * DHID * 4);   // 8 MB split-K partials
    (void)ws_size;

    const int nScanBlk = (N + 255) / 256;
    const int gemmBlk = (N + 63) / 64;
    const int gatherBlk = (N + 15) / 16;
    const int total8 = N * HC / 8;
    const float invN = 1.0f / (float)N;
    const int rangeSize = (N + NSCAT - 1) / NSCAT;

    hipMemsetAsync(colstats, 0, zeroBytes, stream);

    // ---- weight prep + x conversion ----
    k_xtobf<<<(N * FIN / 4 + 255) / 256, 256, 0, stream>>>(x, xb, N * FIN / 4);
    k_wprep_all<<<(FIN * HC + 2 * HC * HC + 255) / 256, 256, 0, stream>>>(
        W1, W2, W3, wt1h, wt1l, wt2h, wt2l, wt3h, wt3l);
    k_wprep2<<<dim3(ZKP / 32, DHID / 32), 256, 0, stream>>>(Wd0, wd0h, wd0l, ZK, ZKP, DHID);
    k_wprep2<<<dim3(DHID / 32, DHID / 32), 256, 0, stream>>>(Wd1, wd1h, wd1l, DHID, DHID, DHID);
    k_wprep2<<<dim3(DHID / 32, DHID / 32), 256, 0, stream>>>(Wd2, wd2h, wd2l, DHID, DHID, DHID);

    // ---- CSR build ----
    k_deg_i<<<(E + 255) / 256, 256, 0, stream>>>(dst, degcnt, E);
    k_scan1<<<nScanBlk, 256, 0, stream>>>(degcnt, part, bsum, dinv, N);
    k_scan2<<<1, 256, 0, stream>>>(bsum, nScanBlk);
    k_scan3<<<nScanBlk, 256, 0, stream>>>(part, bsum, row_start, cur, N);
    k_scatter2<<<dim3((E + 255) / 256, NSCAT), 256, 0, stream>>>(src, dst, dinv, cur, csr,
                                                                 E, rangeSize);

    // ---- layer 1: gather(x) -> gemm -> stats0 ----
    k_gather2b<FIN><<<gatherBlk, 256, 0, stream>>>(xb, csr, row_start, degcnt, dinv, aggx, N);
    gemm_node2<FIN><<<gemmBlk, 512, 0, stream>>>(aggx, wt1h, wt1l, tabA, N);
    k_bn_reduce2<<<256, 256, 0, stream>>>(tabA, colstats + 0 * 2 * HC, N);

    // ---- layer 2: BN1 apply (inline stats) -> gemm -> gather -> stats1 ----
    k_bn_apply3<<<(total8 + 255) / 256, 256, 0, stream>>>(tabA, colstats + 0 * 2 * HC,
                                                          g1, be1, invN, total8);
    gemm_node2<HC><<<gemmBlk, 512, 0, stream>>>(tabA, wt2h, wt2l, tabB, N);
    k_gather2b<HC><<<gatherBlk, 256, 0, stream>>>(tabB, csr, row_start, degcnt, dinv, tabA, N);
    k_bn_reduce2<<<256, 256, 0, stream>>>(tabA, colstats + 1 * 2 * HC, N);

    // ---- layer 3 ----
    k_bn_apply3<<<(total8 + 255) / 256, 256, 0, stream>>>(tabA, colstats + 1 * 2 * HC,
                                                          g2, be2, invN, total8);
    gemm_node2<HC><<<gemmBlk, 512, 0, stream>>>(tabA, wt3h, wt3l, tabB, N);
    k_gather2b<HC><<<gatherBlk, 256, 0, stream>>>(tabB, csr, row_start, degcnt, dinv, tabA, N);
    k_bn_reduce2<<<256, 256, 0, stream>>>(tabA, colstats + 2 * 2 * HC, N);

    // ---- pool (BN3 inline) + z ----
    k_pool<<<512, HC, 0, stream>>>(tabA, batch, colstats + 2 * 2 * HC, g3, be3, invN,
                                   pooled, cntf, N);
    k_build_z<<<G, 192, 0, stream>>>(pooled, cntf, origin, direction, zbuf, G);

    // ---- dense head: split-K MFMA + reduce ----
    const int MN = G * DHID;
    const int rblk = (MN / 4 + 255) / 256;

    gemm_head_sk<<<dim3(DHID / 64, (G + 31) / 32, 5), 256, 0, stream>>>(
        zbuf, wd0h, wd0l, kpart, G, DHID, ZKP, 32);
    k_reduce_br<<<rblk, 256, 0, stream>>>(kpart, bd0, t0, MN, DHID - 1, 5);

    gemm_head_sk<<<dim3(DHID / 64, (G + 31) / 32, 8), 256, 0, stream>>>(
        t0, wd1h, wd1l, kpart, G, DHID, DHID, 128);
    k_reduce_br<<<rblk, 256, 0, stream>>>(kpart, bd1, t1, MN, DHID - 1, 8);

    gemm_head_sk<<<dim3(DHID / 64, (G + 31) / 32, 8), 256, 0, stream>>>(
        t1, wd2h, wd2l, kpart, G, DHID, DHID, 128);
    k_reduce_br<<<rblk, 256, 0, stream>>>(kpart, bd2, t0, MN, DHID - 1, 8);

    k_dense_out<<<G, 256, 0, stream>>>(t0, Wout, bout, out, DHID);
}

// Round 10
// 404.662 us; speedup vs baseline: 1.3250x; 1.3250x over previous
//
#include <hip/hip_runtime.h>

#define HC 128      // hidden / latent channels
#define FIN 64
#define DHID 1024
#define ZK 134      // LAT + 6
#define ZKP 160     // ZK padded to multiple of 32 for MFMA head
#define NSCAT 4     // dst-range partitions for scatter write locality

typedef __attribute__((ext_vector_type(8))) short short8;
typedef __attribute__((ext_vector_type(8))) __bf16 bf16x8;
typedef __attribute__((ext_vector_type(4))) float f32x4;
typedef __attribute__((ext_vector_type(8))) unsigned short u16x8;
typedef __attribute__((ext_vector_type(4))) unsigned short u16x4;

union FragU { short8 s; bf16x8 b; u16x8 u; };

__device__ inline unsigned short rne_bf16(float x) {
    union { float f; unsigned u; } v; v.f = x;
    unsigned u = v.u;
    unsigned r = (u + 0x7fffu + ((u >> 16) & 1u)) >> 16;
    return (unsigned short)r;
}
__device__ inline float bf16_to_f(unsigned short h) {
    union { unsigned u; float f; } v; v.u = ((unsigned)h) << 16;
    return v.f;
}

// ---------------------------------------------------------------- small utils
__global__ void k_deg_i(const int* __restrict__ dst, int* __restrict__ cnt, int E) {
    int i = blockIdx.x * blockDim.x + threadIdx.x;
    if (i < E) atomicAdd(&cnt[dst[i]], 1);
}

// x fp32 -> bf16 table
__global__ void k_xtobf(const float* __restrict__ x, unsigned short* __restrict__ xb, int n4) {
    int i = blockIdx.x * blockDim.x + threadIdx.x;
    if (i >= n4) return;
    float4 v = ((const float4*)x)[i];
    u16x4 o;
    o[0] = rne_bf16(v.x); o[1] = rne_bf16(v.y);
    o[2] = rne_bf16(v.z); o[3] = rne_bf16(v.w);
    ((u16x4*)xb)[i] = o;
}

// ---------------------------------------------------------------- scan (CSR row offsets) + dinv
__global__ void k_scan1(const int* __restrict__ cnt, int* __restrict__ part,
                        int* __restrict__ bsum, float* __restrict__ dinv, int N) {
    __shared__ int sh[256];
    int t = threadIdx.x, i = blockIdx.x * 256 + t;
    int v = (i < N) ? cnt[i] : 0;
    if (i < N) dinv[i] = rsqrtf((float)v + 1.0f);
    sh[t] = v; __syncthreads();
    #pragma unroll
    for (int off = 1; off < 256; off <<= 1) {
        int tv = (t >= off) ? sh[t - off] : 0;
        __syncthreads();
        sh[t] += tv;
        __syncthreads();
    }
    if (i < N) part[i] = sh[t] - v;
    if (t == 255) bsum[blockIdx.x] = sh[255];
}

__global__ void k_scan2(int* __restrict__ bsum, int nb) {
    __shared__ int sh[256];
    int t = threadIdx.x;
    int v = (t < nb) ? bsum[t] : 0;
    sh[t] = v; __syncthreads();
    #pragma unroll
    for (int off = 1; off < 256; off <<= 1) {
        int tv = (t >= off) ? sh[t - off] : 0;
        __syncthreads();
        sh[t] += tv;
        __syncthreads();
    }
    if (t < nb) bsum[t] = sh[t] - v;
}

// row_start AND cur both get the exclusive-scan value (cur is the live cursor)
__global__ void k_scan3(const int* __restrict__ part, const int* __restrict__ bsum,
                        int* __restrict__ row_start, int* __restrict__ cur, int N) {
    int i = blockIdx.x * 256 + threadIdx.x;
    if (i < N) { int v = part[i] + bsum[blockIdx.x]; row_start[i] = v; cur[i] = v; }
}

// dst-range-partitioned scatter: pos comes straight from the atomic (cur pre-seeded
// with row_start). blockIdx.y selects the dst range -> csr/cur writes stay L2-local.
__global__ void k_scatter2(const int* __restrict__ src, const int* __restrict__ dst,
                           const float* __restrict__ dinv,
                           int* __restrict__ cur, int2* __restrict__ csr,
                           int E, int rangeSize) {
    int e = blockIdx.x * blockDim.x + threadIdx.x;
    if (e >= E) return;
    int d = dst[e];
    int lo = blockIdx.y * rangeSize;
    if (d < lo || d >= lo + rangeSize) return;
    int s = src[e];
    int pos = atomicAdd(&cur[d], 1);
    int2 pk; pk.x = s; pk.y = __float_as_int(dinv[s] * dinv[d]);
    csr[pos] = pk;
}

// ---------------------------------------------------------------- gather (bf16 table -> bf16 out, fp32 accum)
template <int RF> struct BVec;
template <> struct BVec<64>  { using T = u16x4; static const int VPL = 4; };
template <> struct BVec<128> { using T = u16x8; static const int VPL = 8; };

// quarter-wave (16 lanes) per node; lane reads RF/16 features as one vector
template <int RF>
__global__ __launch_bounds__(256) void k_gather2b(const unsigned short* __restrict__ T,
                                                  const int2* __restrict__ csr,
                                                  const int* __restrict__ row_start,
                                                  const int* __restrict__ cnt,
                                                  const float* __restrict__ dinv,
                                                  unsigned short* __restrict__ agg, int N) {
    using vec = typename BVec<RF>::T;
    constexpr int VPL = BVec<RF>::VPL;
    int tid = threadIdx.x;
    int node = blockIdx.x * 16 + (tid >> 4);
    int q = tid & 15;
    if (node >= N) return;
    int beg = row_start[node];
    int end = beg + cnt[node];
    float d = dinv[node];
    vec sv = ((const vec*)(T + (size_t)node * RF))[q];
    float acc[VPL];
    #pragma unroll
    for (int i = 0; i < VPL; ++i) acc[i] = bf16_to_f(sv[i]) * d * d;
    int j = beg;
    for (; j + 8 <= end; j += 8) {
        int2 e[8];
        #pragma unroll
        for (int u = 0; u < 8; ++u) e[u] = csr[j + u];
        vec v[8];
        #pragma unroll
        for (int u = 0; u < 8; ++u) v[u] = ((const vec*)(T + (size_t)e[u].x * RF))[q];
        #pragma unroll
        for (int u = 0; u < 8; ++u) {
            float nn = __int_as_float(e[u].y);
            #pragma unroll
            for (int i = 0; i < VPL; ++i) acc[i] += bf16_to_f(v[u][i]) * nn;
        }
    }
    for (; j + 2 <= end; j += 2) {
        int2 e0 = csr[j], e1 = csr[j + 1];
        vec v0 = ((const vec*)(T + (size_t)e0.x * RF))[q];
        vec v1 = ((const vec*)(T + (size_t)e1.x * RF))[q];
        float n0 = __int_as_float(e0.y), n1 = __int_as_float(e1.y);
        #pragma unroll
        for (int i = 0; i < VPL; ++i)
            acc[i] += bf16_to_f(v0[i]) * n0 + bf16_to_f(v1[i]) * n1;
    }
    if (j < end) {
        int2 e0 = csr[j];
        vec v0 = ((const vec*)(T + (size_t)e0.x * RF))[q];
        float n0 = __int_as_float(e0.y);
        #pragma unroll
        for (int i = 0; i < VPL; ++i) acc[i] += bf16_to_f(v0[i]) * n0;
    }
    vec o;
    #pragma unroll
    for (int i = 0; i < VPL; ++i) o[i] = rne_bf16(acc[i]);
    ((vec*)(agg + (size_t)node * RF))[q] = o;
}

// ---------------------------------------------------------------- batchnorm stats
// u16x8 loads, NAMED scalar accumulators (keeps them in VGPRs — array form spilled
// to scratch at VGPR_Count=20 and ran 55us), two-phase LDS reduce.
__global__ __launch_bounds__(256) void k_bn_reduce3(const unsigned short* __restrict__ x,
                                                    float* __restrict__ stat, int N) {
    int cg = threadIdx.x & 15;        // col group: cols cg*8 .. cg*8+7
    int rr = threadIdx.x >> 4;        // 0..15
    int rpb = (N + gridDim.x - 1) / gridDim.x;
    int r0 = blockIdx.x * rpb;
    int r1 = min(N, r0 + rpb);
    float s0=0.f,s1=0.f,s2=0.f,s3=0.f,s4=0.f,s5=0.f,s6=0.f,s7=0.f;
    float q0=0.f,q1=0.f,q2=0.f,q3=0.f,q4=0.f,q5=0.f,q6=0.f,q7=0.f;
    for (int r = r0 + rr; r < r1; r += 16) {
        u16x8 v = *(const u16x8*)(x + (size_t)r * HC + cg * 8);
        float f;
        f = bf16_to_f(v[0]); s0 += f; q0 += f * f;
        f = bf16_to_f(v[1]); s1 += f; q1 += f * f;
        f = bf16_to_f(v[2]); s2 += f; q2 += f * f;
        f = bf16_to_f(v[3]); s3 += f; q3 += f * f;
        f = bf16_to_f(v[4]); s4 += f; q4 += f * f;
        f = bf16_to_f(v[5]); s5 += f; q5 += f * f;
        f = bf16_to_f(v[6]); s6 += f; q6 += f * f;
        f = bf16_to_f(v[7]); s7 += f; q7 += f * f;
    }
    __shared__ float sh[16][136];     // [rr][col], padded
    int c0 = cg * 8;
    int tid = threadIdx.x;
    // phase 1: sums
    sh[rr][c0+0]=s0; sh[rr][c0+1]=s1; sh[rr][c0+2]=s2; sh[rr][c0+3]=s3;
    sh[rr][c0+4]=s4; sh[rr][c0+5]=s5; sh[rr][c0+6]=s6; sh[rr][c0+7]=s7;
    __syncthreads();
    if (tid < HC) {
        float tot = 0.f;
        #pragma unroll
        for (int r2 = 0; r2 < 16; ++r2) tot += sh[r2][tid];
        atomicAdd(&stat[tid], tot);
    }
    __syncthreads();
    // phase 2: sumsq
    sh[rr][c0+0]=q0; sh[rr][c0+1]=q1; sh[rr][c0+2]=q2; sh[rr][c0+3]=q3;
    sh[rr][c0+4]=q4; sh[rr][c0+5]=q5; sh[rr][c0+6]=q6; sh[rr][c0+7]=q7;
    __syncthreads();
    if (tid < HC) {
        float tot = 0.f;
        #pragma unroll
        for (int r2 = 0; r2 < 16; ++r2) tot += sh[r2][tid];
        atomicAdd(&stat[HC + tid], tot);
    }
}

// in-place BN+ReLU on bf16 table; scale/shift recomputed inline from stats (cheap)
__global__ void k_bn_apply3(unsigned short* __restrict__ t, const float* __restrict__ stat,
                            const float* __restrict__ gam, const float* __restrict__ bet,
                            float invN, int total8) {
    int i = blockIdx.x * blockDim.x + threadIdx.x;
    if (i >= total8) return;
    int k0 = (i * 8) & (HC - 1);
    u16x8 v = ((const u16x8*)t)[i];
    u16x8 o;
    #pragma unroll
    for (int j = 0; j < 8; ++j) {
        int k = k0 + j;
        float m = stat[k] * invN;
        float var = stat[HC + k] * invN - m * m;
        float istd = rsqrtf(var + 1e-5f);
        float sc = gam[k] * istd;
        float sh = bet[k] - m * sc;
        o[j] = rne_bf16(fmaxf(bf16_to_f(v[j]) * sc + sh, 0.f));
    }
    ((u16x8*)t)[i] = o;
}

// ---------------------------------------------------------------- pooling (BN3 inline, bf16 input)
__global__ void k_pool(const unsigned short* __restrict__ h, const int* __restrict__ batch,
                       const float* __restrict__ stat, const float* __restrict__ gam,
                       const float* __restrict__ bet, float invN,
                       float* __restrict__ pooled, float* __restrict__ cnt, int N) {
    int t = threadIdx.x;  // 0..127
    float m = stat[t] * invN;
    float var = stat[HC + t] * invN - m * m;
    float istd = rsqrtf(var + 1e-5f);
    float scv = gam[t] * istd;
    float shv = bet[t] - m * scv;
    int rpb = (N + gridDim.x - 1) / gridDim.x;
    int r0 = blockIdx.x * rpb;
    int r1 = min(N, r0 + rpb);
    if (r0 >= r1) return;
    int curb = batch[r0];
    float acc = 0.f; float c = 0.f;
    for (int r = r0; r < r1; ++r) {
        int b = batch[r];
        if (b != curb) {
            atomicAdd(&pooled[curb * HC + t], acc);
            if (t == 0) atomicAdd(&cnt[curb], c);
            curb = b; acc = 0.f; c = 0.f;
        }
        acc += bf16_to_f(h[(size_t)r * HC + t]) * scv + shv;
        c += 1.f;
    }
    atomicAdd(&pooled[curb * HC + t], acc);
    if (t == 0) atomicAdd(&cnt[curb], c);
}

// build z padded to ZKP cols (pad = 0)
__global__ void k_build_z(const float* __restrict__ pooled, const float* __restrict__ cnt,
                          const float* __restrict__ origin, const float* __restrict__ dir,
                          float* __restrict__ z, int G) {
    int g = blockIdx.x;
    int t = threadIdx.x;
    if (t >= ZKP) return;
    float v = 0.f;
    if (t < HC) {
        float c = fmaxf(cnt[g], 1.0f);
        v = pooled[g * HC + t] / c;
    } else if (t < HC + 3) {
        v = origin[g * 3 + (t - HC)];
    } else if (t < HC + 6) {
        v = dir[g * 3 + (t - HC - 3)];
    }
    z[g * ZKP + t] = v;
}

// ---------------------------------------------------------------- W prep (all 3 GCN weights): fp32 [K][128] -> bf16 hi/lo transposed [128][K]
__global__ void k_wprep_all(const float* __restrict__ W1, const float* __restrict__ W2,
                            const float* __restrict__ W3,
                            unsigned short* __restrict__ w1h, unsigned short* __restrict__ w1l,
                            unsigned short* __restrict__ w2h, unsigned short* __restrict__ w2l,
                            unsigned short* __restrict__ w3h, unsigned short* __restrict__ w3l) {
    int i = blockIdx.x * blockDim.x + threadIdx.x;
    const float* W; unsigned short *th, *tl; int K, idx;
    if (i < FIN * HC)           { W = W1; th = w1h; tl = w1l; K = FIN; idx = i; }
    else if (i < FIN*HC + HC*HC){ W = W2; th = w2h; tl = w2l; K = HC;  idx = i - FIN*HC; }
    else if (i < FIN*HC + 2*HC*HC){ W = W3; th = w3h; tl = w3l; K = HC; idx = i - FIN*HC - HC*HC; }
    else return;
    int k = idx >> 7, n = idx & (HC - 1);
    float w = W[idx];
    unsigned short h = rne_bf16(w);
    th[n * K + k] = h;
    tl[n * K + k] = rne_bf16(w - bf16_to_f(h));
}

// ---------------------------------------------------------------- W prep (head): fp32 [K][NC] -> bf16 hi/lo transposed [NC][KP]
__global__ __launch_bounds__(256) void k_wprep2(const float* __restrict__ W,
                                                unsigned short* __restrict__ th,
                                                unsigned short* __restrict__ tl,
                                                int K, int KP, int NC) {
    __shared__ float tile[32][33];
    int kt = blockIdx.x * 32, nt = blockIdx.y * 32;
    int tx = threadIdx.x & 31, ty0 = threadIdx.x >> 5;
    #pragma unroll
    for (int i = 0; i < 4; ++i) {
        int ty = ty0 + i * 8;
        int k = kt + ty;
        float v = (k < K) ? W[(size_t)k * NC + nt + tx] : 0.f;
        tile[ty][tx] = v;
    }
    __syncthreads();
    #pragma unroll
    for (int i = 0; i < 4; ++i) {
        int ty = ty0 + i * 8;
        int n = nt + ty;
        int k = kt + tx;
        float w = tile[tx][ty];
        unsigned short h = rne_bf16(w);
        th[(size_t)n * KP + k] = h;
        tl[(size_t)n * KP + k] = rne_bf16(w - bf16_to_f(h));
    }
}

// ---------------------------------------------------------------- MFMA node GEMM (pure bf16 A)
// C[M,128] = A[M,KK] @ W[KK,128]; A raw bf16 (BN pre-applied), W hi/lo split.
// 512 thr = 8 waves (2 row x 4 col); wave = 16 rows x 32 cols; 64 rows/block.
template <int KK>
__global__ __launch_bounds__(512) void gemm_node2(const unsigned short* __restrict__ A,
                                                  const unsigned short* __restrict__ wth,
                                                  const unsigned short* __restrict__ wtl,
                                                  unsigned short* __restrict__ C, int M) {
    constexpr int KS = KK / 32;
    int tid = threadIdx.x;
    int lane = tid & 63, wid = tid >> 6;
    int rw = wid & 1, cg = wid >> 1;          // rw 0/1, cg 0..3
    int l15 = lane & 15, l4 = lane >> 4;
    int cbase = cg * 32;

    FragU bh[2][KS], bl[2][KS];
    #pragma unroll
    for (int ct = 0; ct < 2; ++ct) {
        int n = cbase + ct * 16 + l15;
        #pragma unroll
        for (int ks = 0; ks < KS; ++ks) {
            int k = ks * 32 + l4 * 8;
            bh[ct][ks].s = *(const short8*)(wth + (size_t)n * KK + k);
            bl[ct][ks].s = *(const short8*)(wtl + (size_t)n * KK + k);
        }
    }

    #pragma unroll
    for (int rt = 0; rt < 2; ++rt) {
        int m0 = blockIdx.x * 64 + rt * 32 + rw * 16;
        if (m0 < M) {
            int arow = min(m0 + l15, M - 1);
            f32x4 zero = {0.f, 0.f, 0.f, 0.f};
            f32x4 acc[2] = {zero, zero};
            #pragma unroll
            for (int ks = 0; ks < KS; ++ks) {
                int k0 = ks * 32 + l4 * 8;
                FragU a;
                a.u = *(const u16x8*)(A + (size_t)arow * KK + k0);
                #pragma unroll
                for (int ct = 0; ct < 2; ++ct) {
                    acc[ct] = __builtin_amdgcn_mfma_f32_16x16x32_bf16(a.b, bh[ct][ks].b, acc[ct], 0, 0, 0);
                    acc[ct] = __builtin_amdgcn_mfma_f32_16x16x32_bf16(a.b, bl[ct][ks].b, acc[ct], 0, 0, 0);
                }
            }
            #pragma unroll
            for (int ct = 0; ct < 2; ++ct) {
                int col = cbase + ct * 16 + l15;
                #pragma unroll
                for (int r = 0; r < 4; ++r) {
                    int row = m0 + l4 * 4 + r;
                    if (row < M)
                        C[(size_t)row * HC + col] = rne_bf16(acc[ct][r]);
                }
            }
        }
    }
}

// ---------------------------------------------------------------- MFMA head GEMM, split-K
__global__ __launch_bounds__(256) void gemm_head_sk(const float* __restrict__ A,
                                                    const unsigned short* __restrict__ wth,
                                                    const unsigned short* __restrict__ wtl,
                                                    float* __restrict__ Cpart,
                                                    int M, int N, int K, int slice) {
    int tid = threadIdx.x;
    int lane = tid & 63, wid = tid >> 6;
    int rw = wid & 1, cw = wid >> 1;
    int l15 = lane & 15, l4 = lane >> 4;
    int m0 = blockIdx.y * 32 + rw * 16;
    int cb = blockIdx.x * 64 + cw * 32;
    int z = blockIdx.z;
    int kbeg = z * slice;
    int kend = min(K, kbeg + slice);
    if (m0 >= M) return;

    int arow = m0 + l15;
    f32x4 zero = {0.f, 0.f, 0.f, 0.f};
    f32x4 acc[2] = {zero, zero};

    for (int k0 = kbeg; k0 < kend; k0 += 32) {
        int ka = k0 + l4 * 8;
        const float4 p0 = *(const float4*)(A + (size_t)arow * K + ka);
        const float4 p1 = *(const float4*)(A + (size_t)arow * K + ka + 4);
        float av[8] = {p0.x, p0.y, p0.z, p0.w, p1.x, p1.y, p1.z, p1.w};
        FragU ah, al;
        #pragma unroll
        for (int i = 0; i < 8; ++i) {
            unsigned short h = rne_bf16(av[i]);
            ah.s[i] = (short)h;
            al.s[i] = (short)rne_bf16(av[i] - bf16_to_f(h));
        }
        #pragma unroll
        for (int ct = 0; ct < 2; ++ct) {
            int n = cb + ct * 16 + l15;
            FragU bh, bl;
            bh.s = *(const short8*)(wth + (size_t)n * K + ka);
            bl.s = *(const short8*)(wtl + (size_t)n * K + ka);
            acc[ct] = __builtin_amdgcn_mfma_f32_16x16x32_bf16(ah.b, bh.b, acc[ct], 0, 0, 0);
            acc[ct] = __builtin_amdgcn_mfma_f32_16x16x32_bf16(ah.b, bl.b, acc[ct], 0, 0, 0);
            acc[ct] = __builtin_amdgcn_mfma_f32_16x16x32_bf16(al.b, bh.b, acc[ct], 0, 0, 0);
        }
    }

    float* Cz = Cpart + (size_t)z * M * N;
    #pragma unroll
    for (int ct = 0; ct < 2; ++ct) {
        int col = cb + ct * 16 + l15;
        #pragma unroll
        for (int r = 0; r < 4; ++r) {
            int row = m0 + l4 * 4 + r;
            Cz[(size_t)row * N + col] = acc[ct][r];
        }
    }
}

// sum NZ partials + bias + relu; N power of two (DHID)
__global__ void k_reduce_br(const float* __restrict__ part, const float* __restrict__ bias,
                            float* __restrict__ C, int MN, int Nmask, int NZ) {
    int i = (blockIdx.x * blockDim.x + threadIdx.x) * 4;
    if (i >= MN) return;
    float4 acc = *(const float4*)(part + i);
    for (int zz = 1; zz < NZ; ++zz) {
        float4 p = *(const float4*)(part + (size_t)zz * MN + i);
        acc.x += p.x; acc.y += p.y; acc.z += p.z; acc.w += p.w;
    }
    int n = i & Nmask;
    acc.x += bias[n]; acc.y += bias[n + 1]; acc.z += bias[n + 2]; acc.w += bias[n + 3];
    acc.x = fmaxf(acc.x, 0.f); acc.y = fmaxf(acc.y, 0.f);
    acc.z = fmaxf(acc.z, 0.f); acc.w = fmaxf(acc.w, 0.f);
    *(float4*)(C + i) = acc;
}

// final [G,DH] @ [DH,3] + bout
__global__ void k_dense_out(const float* __restrict__ z, const float* __restrict__ W,
                            const float* __restrict__ b, float* __restrict__ out, int K) {
    int g = blockIdx.x;
    const float* zr = z + (size_t)g * K;
    float a0 = 0.f, a1 = 0.f, a2 = 0.f;
    for (int k = threadIdx.x; k < K; k += blockDim.x) {
        float zv = zr[k];
        a0 += zv * W[k * 3 + 0];
        a1 += zv * W[k * 3 + 1];
        a2 += zv * W[k * 3 + 2];
    }
    __shared__ float s[768];
    s[threadIdx.x] = a0; s[256 + threadIdx.x] = a1; s[512 + threadIdx.x] = a2;
    __syncthreads();
    for (int off = 128; off > 0; off >>= 1) {
        if ((int)threadIdx.x < off) {
            s[threadIdx.x]       += s[threadIdx.x + off];
            s[256 + threadIdx.x] += s[256 + threadIdx.x + off];
            s[512 + threadIdx.x] += s[512 + threadIdx.x + off];
        }
        __syncthreads();
    }
    if (threadIdx.x == 0) {
        out[g * 3 + 0] = s[0]   + b[0];
        out[g * 3 + 1] = s[256] + b[1];
        out[g * 3 + 2] = s[512] + b[2];
    }
}

// ---------------------------------------------------------------- launch
extern "C" void kernel_launch(void* const* d_in, const int* in_sizes, int n_in,
                              void* d_out, int out_size, void* d_ws, size_t ws_size,
                              hipStream_t stream) {
    const float* x         = (const float*)d_in[0];
    const float* origin    = (const float*)d_in[1];
    const float* direction = (const float*)d_in[2];
    const int*   eidx      = (const int*)d_in[3];
    const int*   batch     = (const int*)d_in[4];
    const float* W1 = (const float*)d_in[5];
    const float* W2 = (const float*)d_in[7];
    const float* W3 = (const float*)d_in[9];
    const float* g1 = (const float*)d_in[11]; const float* be1 = (const float*)d_in[12];
    const float* g2 = (const float*)d_in[13]; const float* be2 = (const float*)d_in[14];
    const float* g3 = (const float*)d_in[15]; const float* be3 = (const float*)d_in[16];
    const float* Wd0 = (const float*)d_in[17]; const float* bd0 = (const float*)d_in[18];
    const float* Wd1 = (const float*)d_in[19]; const float* bd1 = (const float*)d_in[20];
    const float* Wd2 = (const float*)d_in[21]; const float* bd2 = (const float*)d_in[22];
    const float* Wout = (const float*)d_in[23]; const float* bout = (const float*)d_in[24];
    float* out = (float*)d_out;

    const int N = in_sizes[4];
    const int E = in_sizes[3] / 2;
    const int G = in_sizes[1] / 3;
    const int* src = eidx;
    const int* dst = eidx + E;

    char* ws = (char*)d_ws;
    size_t off = 0;
    auto alloc = [&](size_t nbytes) -> void* {
        void* p = (void*)(ws + off);
        off += (nbytes + 255) & ~(size_t)255;
        return p;
    };
    // zero-init region (one memset): colstats | pooled | cntf | degcnt
    float* colstats = (float*)alloc(3 * 2 * HC * 4);
    float* pooled   = (float*)alloc((size_t)G * HC * 4);
    float* cntf     = (float*)alloc((size_t)G * 4);
    int*   degcnt   = (int*)alloc((size_t)N * 4);
    const size_t zeroBytes = 3 * 2 * HC * 4 + (size_t)G * HC * 4 + 1024 /*cntf pad*/ + (size_t)N * 4;

    float* dinv     = (float*)alloc((size_t)N * 4);
    int*   part     = (int*)alloc((size_t)N * 4);
    int*   bsum     = (int*)alloc(256 * 4);
    int*   row_start= (int*)alloc((size_t)N * 4);
    int*   cur      = (int*)alloc((size_t)N * 4);
    int2*  csr      = (int2*)alloc((size_t)E * 8);
    unsigned short* xb   = (unsigned short*)alloc((size_t)N * FIN * 2);
    unsigned short* aggx = (unsigned short*)alloc((size_t)N * FIN * 2);
    unsigned short* tabA = (unsigned short*)alloc((size_t)N * HC * 2);
    unsigned short* tabB = (unsigned short*)alloc((size_t)N * HC * 2);
    unsigned short* wt1h = (unsigned short*)alloc((size_t)FIN * HC * 2);
    unsigned short* wt1l = (unsigned short*)alloc((size_t)FIN * HC * 2);
    unsigned short* wt2h = (unsigned short*)alloc((size_t)HC * HC * 2);
    unsigned short* wt2l = (unsigned short*)alloc((size_t)HC * HC * 2);
    unsigned short* wt3h = (unsigned short*)alloc((size_t)HC * HC * 2);
    unsigned short* wt3l = (unsigned short*)alloc((size_t)HC * HC * 2);
    unsigned short* wd0h = (unsigned short*)alloc((size_t)DHID * ZKP * 2);
    unsigned short* wd0l = (unsigned short*)alloc((size_t)DHID * ZKP * 2);
    unsigned short* wd1h = (unsigned short*)alloc((size_t)DHID * DHID * 2);
    unsigned short* wd1l = (unsigned short*)alloc((size_t)DHID * DHID * 2);
    unsigned short* wd2h = (unsigned short*)alloc((size_t)DHID * DHID * 2);
    unsigned short* wd2l = (unsigned short*)alloc((size_t)DHID * DHID * 2);
    float* zbuf     = (float*)alloc((size_t)G * ZKP * 4);
    float* t0       = (float*)alloc((size_t)G * DHID * 4);
    float* t1       = (float*)alloc((size_t)G * DHID * 4);
    float* kpart    = (float*)alloc((size_t)8 * G * DHID * 4);   // 8 MB split-K partials
    (void)ws_size;

    const int nScanBlk = (N + 255) / 256;
    const int gemmBlk = (N + 63) / 64;
    const int gatherBlk = (N + 15) / 16;
    const int total8 = N * HC / 8;
    const float invN = 1.0f / (float)N;
    const int rangeSize = (N + NSCAT - 1) / NSCAT;

    hipMemsetAsync(colstats, 0, zeroBytes, stream);

    // ---- weight prep + x conversion ----
    k_xtobf<<<(N * FIN / 4 + 255) / 256, 256, 0, stream>>>(x, xb, N * FIN / 4);
    k_wprep_all<<<(FIN * HC + 2 * HC * HC + 255) / 256, 256, 0, stream>>>(
        W1, W2, W3, wt1h, wt1l, wt2h, wt2l, wt3h, wt3l);
    k_wprep2<<<dim3(ZKP / 32, DHID / 32), 256, 0, stream>>>(Wd0, wd0h, wd0l, ZK, ZKP, DHID);
    k_wprep2<<<dim3(DHID / 32, DHID / 32), 256, 0, stream>>>(Wd1, wd1h, wd1l, DHID, DHID, DHID);
    k_wprep2<<<dim3(DHID / 32, DHID / 32), 256, 0, stream>>>(Wd2, wd2h, wd2l, DHID, DHID, DHID);

    // ---- CSR build ----
    k_deg_i<<<(E + 255) / 256, 256, 0, stream>>>(dst, degcnt, E);
    k_scan1<<<nScanBlk, 256, 0, stream>>>(degcnt, part, bsum, dinv, N);
    k_scan2<<<1, 256, 0, stream>>>(bsum, nScanBlk);
    k_scan3<<<nScanBlk, 256, 0, stream>>>(part, bsum, row_start, cur, N);
    k_scatter2<<<dim3((E + 255) / 256, NSCAT), 256, 0, stream>>>(src, dst, dinv, cur, csr,
                                                                 E, rangeSize);

    // ---- layer 1: gather(x) -> gemm -> stats0 ----
    k_gather2b<FIN><<<gatherBlk, 256, 0, stream>>>(xb, csr, row_start, degcnt, dinv, aggx, N);
    gemm_node2<FIN><<<gemmBlk, 512, 0, stream>>>(aggx, wt1h, wt1l, tabA, N);
    k_bn_reduce3<<<256, 256, 0, stream>>>(tabA, colstats + 0 * 2 * HC, N);

    // ---- layer 2: BN1 apply (inline stats) -> gemm -> gather -> stats1 ----
    k_bn_apply3<<<(total8 + 255) / 256, 256, 0, stream>>>(tabA, colstats + 0 * 2 * HC,
                                                          g1, be1, invN, total8);
    gemm_node2<HC><<<gemmBlk, 512, 0, stream>>>(tabA, wt2h, wt2l, tabB, N);
    k_gather2b<HC><<<gatherBlk, 256, 0, stream>>>(tabB, csr, row_start, degcnt, dinv, tabA, N);
    k_bn_reduce3<<<256, 256, 0, stream>>>(tabA, colstats + 1 * 2 * HC, N);

    // ---- layer 3 ----
    k_bn_apply3<<<(total8 + 255) / 256, 256, 0, stream>>>(tabA, colstats + 1 * 2 * HC,
                                                          g2, be2, invN, total8);
    gemm_node2<HC><<<gemmBlk, 512, 0, stream>>>(tabA, wt3h, wt3l, tabB, N);
    k_gather2b<HC><<<gatherBlk, 256, 0, stream>>>(tabB, csr, row_start, degcnt, dinv, tabA, N);
    k_bn_reduce3<<<256, 256, 0, stream>>>(tabA, colstats + 2 * 2 * HC, N);

    // ---- pool (BN3 inline) + z ----
    k_pool<<<512, HC, 0, stream>>>(tabA, batch, colstats + 2 * 2 * HC, g3, be3, invN,
                                   pooled, cntf, N);
    k_build_z<<<G, 192, 0, stream>>>(pooled, cntf, origin, direction, zbuf, G);

    // ---- dense head: split-K MFMA + reduce ----
    const int MN = G * DHID;
    const int rblk = (MN / 4 + 255) / 256;

    gemm_head_sk<<<dim3(DHID / 64, (G + 31) / 32, 5), 256, 0, stream>>>(
        zbuf, wd0h, wd0l, kpart, G, DHID, ZKP, 32);
    k_reduce_br<<<rblk, 256, 0, stream>>>(kpart, bd0, t0, MN, DHID - 1, 5);

    gemm_head_sk<<<dim3(DHID / 64, (G + 31) / 32, 8), 256, 0, stream>>>(
        t0, wd1h, wd1l, kpart, G, DHID, DHID, 128);
    k_reduce_br<<<rblk, 256, 0, stream>>>(kpart, bd1, t1, MN, DHID - 1, 8);

    gemm_head_sk<<<dim3(DHID / 64, (G + 31) / 32, 8), 256, 0, stream>>>(
        t1, wd2h, wd2l, kpart, G, DHID, DHID, 128);
    k_reduce_br<<<rblk, 256, 0, stream>>>(kpart, bd2, t0, MN, DHID - 1, 8);

    k_dense_out<<<G, 256, 0, stream>>>(t0, Wout, bout, out, DHID);
}

// Round 11
// 367.666 us; speedup vs baseline: 1.4584x; 1.1006x over previous
//
#include <hip/hip_runtime.h>

#define HC 128      // hidden / latent channels
#define FIN 64
#define DHID 1024
#define ZK 134      // LAT + 6
#define ZKP 160     // ZK padded to multiple of 32 for MFMA head

typedef __attribute__((ext_vector_type(8))) short short8;
typedef __attribute__((ext_vector_type(8))) __bf16 bf16x8;
typedef __attribute__((ext_vector_type(4))) float f32x4;
typedef __attribute__((ext_vector_type(8))) unsigned short u16x8;
typedef __attribute__((ext_vector_type(4))) unsigned short u16x4;

union FragU { short8 s; bf16x8 b; u16x8 u; };

__device__ inline unsigned short rne_bf16(float x) {
    union { float f; unsigned u; } v; v.f = x;
    unsigned u = v.u;
    unsigned r = (u + 0x7fffu + ((u >> 16) & 1u)) >> 16;
    return (unsigned short)r;
}
__device__ inline float bf16_to_f(unsigned short h) {
    union { unsigned u; float f; } v; v.u = ((unsigned)h) << 16;
    return v.f;
}

// ---------------------------------------------------------------- degree + per-edge rank
// rank[e] = old count — gives each edge its deterministic slot without a 2nd atomic pass
__global__ void k_deg_rank(const int* __restrict__ dst, int* __restrict__ cnt,
                           int* __restrict__ rank, int E) {
    int i = blockIdx.x * blockDim.x + threadIdx.x;
    if (i < E) rank[i] = atomicAdd(&cnt[dst[i]], 1);
}

// x fp32 -> bf16 table, pre-scaled by dinv[row] (row = i4/(FIN/4))
__global__ void k_xtobf(const float* __restrict__ x, const float* __restrict__ dinv,
                        unsigned short* __restrict__ xb, int n4) {
    int i = blockIdx.x * blockDim.x + threadIdx.x;
    if (i >= n4) return;
    float d = dinv[i / (FIN / 4)];
    float4 v = ((const float4*)x)[i];
    u16x4 o;
    o[0] = rne_bf16(v.x * d); o[1] = rne_bf16(v.y * d);
    o[2] = rne_bf16(v.z * d); o[3] = rne_bf16(v.w * d);
    ((u16x4*)xb)[i] = o;
}

// ---------------------------------------------------------------- scan (CSR row offsets) + dinv
__global__ void k_scan1(const int* __restrict__ cnt, int* __restrict__ part,
                        int* __restrict__ bsum, float* __restrict__ dinv, int N) {
    __shared__ int sh[256];
    int t = threadIdx.x, i = blockIdx.x * 256 + t;
    int v = (i < N) ? cnt[i] : 0;
    if (i < N) dinv[i] = rsqrtf((float)v + 1.0f);
    sh[t] = v; __syncthreads();
    #pragma unroll
    for (int off = 1; off < 256; off <<= 1) {
        int tv = (t >= off) ? sh[t - off] : 0;
        __syncthreads();
        sh[t] += tv;
        __syncthreads();
    }
    if (i < N) part[i] = sh[t] - v;
    if (t == 255) bsum[blockIdx.x] = sh[255];
}

__global__ void k_scan2(int* __restrict__ bsum, int nb) {
    __shared__ int sh[256];
    int t = threadIdx.x;
    int v = (t < nb) ? bsum[t] : 0;
    sh[t] = v; __syncthreads();
    #pragma unroll
    for (int off = 1; off < 256; off <<= 1) {
        int tv = (t >= off) ? sh[t - off] : 0;
        __syncthreads();
        sh[t] += tv;
        __syncthreads();
    }
    if (t < nb) bsum[t] = sh[t] - v;
}

__global__ void k_scan3(const int* __restrict__ part, const int* __restrict__ bsum,
                        int* __restrict__ row_start, int N) {
    int i = blockIdx.x * 256 + threadIdx.x;
    if (i < N) row_start[i] = part[i] + bsum[blockIdx.x];
}

// atomic-free scatter: pos = row_start[d] + rank[e]
__global__ void k_scatter3(const int* __restrict__ src, const int* __restrict__ dst,
                           const int* __restrict__ rank, const int* __restrict__ row_start,
                           int* __restrict__ csr, int E) {
    int e = blockIdx.x * blockDim.x + threadIdx.x;
    if (e >= E) return;
    int d = dst[e];
    csr[row_start[d] + rank[e]] = src[e];
}

// ---------------------------------------------------------------- gather (pre-scaled bf16 table)
// agg[d] = dinv[d] * (T'[d] + sum T'[src]);  T' already holds dinv-scaled rows.
template <int RF> struct BVec;
template <> struct BVec<64>  { using T = u16x4; static const int VPL = 4; };
template <> struct BVec<128> { using T = u16x8; static const int VPL = 8; };

template <int RF>
__global__ __launch_bounds__(256) void k_gather3(const unsigned short* __restrict__ T,
                                                 const int* __restrict__ csr,
                                                 const int* __restrict__ row_start,
                                                 const int* __restrict__ cnt,
                                                 const float* __restrict__ dinv,
                                                 unsigned short* __restrict__ agg, int N) {
    using vec = typename BVec<RF>::T;
    constexpr int VPL = BVec<RF>::VPL;
    int tid = threadIdx.x;
    int node = blockIdx.x * 16 + (tid >> 4);
    int q = tid & 15;
    if (node >= N) return;
    int beg = row_start[node];
    int end = beg + cnt[node];
    float d = dinv[node];
    vec sv = ((const vec*)(T + (size_t)node * RF))[q];
    float acc[VPL];
    #pragma unroll
    for (int i = 0; i < VPL; ++i) acc[i] = bf16_to_f(sv[i]);
    int j = beg;
    for (; j + 8 <= end; j += 8) {
        int e0 = csr[j], e1 = csr[j+1], e2 = csr[j+2], e3 = csr[j+3];
        int e4 = csr[j+4], e5 = csr[j+5], e6 = csr[j+6], e7 = csr[j+7];
        vec v0 = ((const vec*)(T + (size_t)e0 * RF))[q];
        vec v1 = ((const vec*)(T + (size_t)e1 * RF))[q];
        vec v2 = ((const vec*)(T + (size_t)e2 * RF))[q];
        vec v3 = ((const vec*)(T + (size_t)e3 * RF))[q];
        vec v4 = ((const vec*)(T + (size_t)e4 * RF))[q];
        vec v5 = ((const vec*)(T + (size_t)e5 * RF))[q];
        vec v6 = ((const vec*)(T + (size_t)e6 * RF))[q];
        vec v7 = ((const vec*)(T + (size_t)e7 * RF))[q];
        #pragma unroll
        for (int i = 0; i < VPL; ++i) {
            acc[i] += (bf16_to_f(v0[i]) + bf16_to_f(v1[i]))
                    + (bf16_to_f(v2[i]) + bf16_to_f(v3[i]))
                    + (bf16_to_f(v4[i]) + bf16_to_f(v5[i]))
                    + (bf16_to_f(v6[i]) + bf16_to_f(v7[i]));
        }
    }
    for (; j + 2 <= end; j += 2) {
        int e0 = csr[j], e1 = csr[j + 1];
        vec v0 = ((const vec*)(T + (size_t)e0 * RF))[q];
        vec v1 = ((const vec*)(T + (size_t)e1 * RF))[q];
        #pragma unroll
        for (int i = 0; i < VPL; ++i)
            acc[i] += bf16_to_f(v0[i]) + bf16_to_f(v1[i]);
    }
    if (j < end) {
        int e0 = csr[j];
        vec v0 = ((const vec*)(T + (size_t)e0 * RF))[q];
        #pragma unroll
        for (int i = 0; i < VPL; ++i) acc[i] += bf16_to_f(v0[i]);
    }
    vec o;
    #pragma unroll
    for (int i = 0; i < VPL; ++i) o[i] = rne_bf16(acc[i] * d);
    ((vec*)(agg + (size_t)node * RF))[q] = o;
}

// ---------------------------------------------------------------- batchnorm stats
// u16x8 loads, NAMED scalar accumulators (array form spills to scratch), 2-phase LDS reduce
__global__ __launch_bounds__(256) void k_bn_reduce3(const unsigned short* __restrict__ x,
                                                    float* __restrict__ stat, int N) {
    int cg = threadIdx.x & 15;
    int rr = threadIdx.x >> 4;
    int rpb = (N + gridDim.x - 1) / gridDim.x;
    int r0 = blockIdx.x * rpb;
    int r1 = min(N, r0 + rpb);
    float s0=0.f,s1=0.f,s2=0.f,s3=0.f,s4=0.f,s5=0.f,s6=0.f,s7=0.f;
    float q0=0.f,q1=0.f,q2=0.f,q3=0.f,q4=0.f,q5=0.f,q6=0.f,q7=0.f;
    for (int r = r0 + rr; r < r1; r += 16) {
        u16x8 v = *(const u16x8*)(x + (size_t)r * HC + cg * 8);
        float f;
        f = bf16_to_f(v[0]); s0 += f; q0 += f * f;
        f = bf16_to_f(v[1]); s1 += f; q1 += f * f;
        f = bf16_to_f(v[2]); s2 += f; q2 += f * f;
        f = bf16_to_f(v[3]); s3 += f; q3 += f * f;
        f = bf16_to_f(v[4]); s4 += f; q4 += f * f;
        f = bf16_to_f(v[5]); s5 += f; q5 += f * f;
        f = bf16_to_f(v[6]); s6 += f; q6 += f * f;
        f = bf16_to_f(v[7]); s7 += f; q7 += f * f;
    }
    __shared__ float sh[16][136];
    int c0 = cg * 8;
    int tid = threadIdx.x;
    sh[rr][c0+0]=s0; sh[rr][c0+1]=s1; sh[rr][c0+2]=s2; sh[rr][c0+3]=s3;
    sh[rr][c0+4]=s4; sh[rr][c0+5]=s5; sh[rr][c0+6]=s6; sh[rr][c0+7]=s7;
    __syncthreads();
    if (tid < HC) {
        float tot = 0.f;
        #pragma unroll
        for (int r2 = 0; r2 < 16; ++r2) tot += sh[r2][tid];
        atomicAdd(&stat[tid], tot);
    }
    __syncthreads();
    sh[rr][c0+0]=q0; sh[rr][c0+1]=q1; sh[rr][c0+2]=q2; sh[rr][c0+3]=q3;
    sh[rr][c0+4]=q4; sh[rr][c0+5]=q5; sh[rr][c0+6]=q6; sh[rr][c0+7]=q7;
    __syncthreads();
    if (tid < HC) {
        float tot = 0.f;
        #pragma unroll
        for (int r2 = 0; r2 < 16; ++r2) tot += sh[r2][tid];
        atomicAdd(&stat[HC + tid], tot);
    }
}

// in-place BN+ReLU on bf16 table; scale/shift recomputed inline from stats
__global__ void k_bn_apply3(unsigned short* __restrict__ t, const float* __restrict__ stat,
                            const float* __restrict__ gam, const float* __restrict__ bet,
                            float invN, int total8) {
    int i = blockIdx.x * blockDim.x + threadIdx.x;
    if (i >= total8) return;
    int k0 = (i * 8) & (HC - 1);
    u16x8 v = ((const u16x8*)t)[i];
    u16x8 o;
    #pragma unroll
    for (int j = 0; j < 8; ++j) {
        int k = k0 + j;
        float m = stat[k] * invN;
        float var = stat[HC + k] * invN - m * m;
        float istd = rsqrtf(var + 1e-5f);
        float sc = gam[k] * istd;
        float sh = bet[k] - m * sc;
        o[j] = rne_bf16(fmaxf(bf16_to_f(v[j]) * sc + sh, 0.f));
    }
    ((u16x8*)t)[i] = o;
}

// ---------------------------------------------------------------- pooling (BN3 inline, bf16 input)
__global__ void k_pool(const unsigned short* __restrict__ h, const int* __restrict__ batch,
                       const float* __restrict__ stat, const float* __restrict__ gam,
                       const float* __restrict__ bet, float invN,
                       float* __restrict__ pooled, float* __restrict__ cnt, int N) {
    int t = threadIdx.x;  // 0..127
    float m = stat[t] * invN;
    float var = stat[HC + t] * invN - m * m;
    float istd = rsqrtf(var + 1e-5f);
    float scv = gam[t] * istd;
    float shv = bet[t] - m * scv;
    int rpb = (N + gridDim.x - 1) / gridDim.x;
    int r0 = blockIdx.x * rpb;
    int r1 = min(N, r0 + rpb);
    if (r0 >= r1) return;
    int curb = batch[r0];
    float acc = 0.f; float c = 0.f;
    for (int r = r0; r < r1; ++r) {
        int b = batch[r];
        if (b != curb) {
            atomicAdd(&pooled[curb * HC + t], acc);
            if (t == 0) atomicAdd(&cnt[curb], c);
            curb = b; acc = 0.f; c = 0.f;
        }
        acc += bf16_to_f(h[(size_t)r * HC + t]) * scv + shv;
        c += 1.f;
    }
    atomicAdd(&pooled[curb * HC + t], acc);
    if (t == 0) atomicAdd(&cnt[curb], c);
}

// build z padded to ZKP cols (pad = 0)
__global__ void k_build_z(const float* __restrict__ pooled, const float* __restrict__ cnt,
                          const float* __restrict__ origin, const float* __restrict__ dir,
                          float* __restrict__ z, int G) {
    int g = blockIdx.x;
    int t = threadIdx.x;
    if (t >= ZKP) return;
    float v = 0.f;
    if (t < HC) {
        float c = fmaxf(cnt[g], 1.0f);
        v = pooled[g * HC + t] / c;
    } else if (t < HC + 3) {
        v = origin[g * 3 + (t - HC)];
    } else if (t < HC + 6) {
        v = dir[g * 3 + (t - HC - 3)];
    }
    z[g * ZKP + t] = v;
}

// ---------------------------------------------------------------- W prep (all 3 GCN weights)
__global__ void k_wprep_all(const float* __restrict__ W1, const float* __restrict__ W2,
                            const float* __restrict__ W3,
                            unsigned short* __restrict__ w1h, unsigned short* __restrict__ w1l,
                            unsigned short* __restrict__ w2h, unsigned short* __restrict__ w2l,
                            unsigned short* __restrict__ w3h, unsigned short* __restrict__ w3l) {
    int i = blockIdx.x * blockDim.x + threadIdx.x;
    const float* W; unsigned short *th, *tl; int K, idx;
    if (i < FIN * HC)           { W = W1; th = w1h; tl = w1l; K = FIN; idx = i; }
    else if (i < FIN*HC + HC*HC){ W = W2; th = w2h; tl = w2l; K = HC;  idx = i - FIN*HC; }
    else if (i < FIN*HC + 2*HC*HC){ W = W3; th = w3h; tl = w3l; K = HC; idx = i - FIN*HC - HC*HC; }
    else return;
    int k = idx >> 7, n = idx & (HC - 1);
    float w = W[idx];
    unsigned short h = rne_bf16(w);
    th[n * K + k] = h;
    tl[n * K + k] = rne_bf16(w - bf16_to_f(h));
}

// ---------------------------------------------------------------- W prep (head)
__global__ __launch_bounds__(256) void k_wprep2(const float* __restrict__ W,
                                                unsigned short* __restrict__ th,
                                                unsigned short* __restrict__ tl,
                                                int K, int KP, int NC) {
    __shared__ float tile[32][33];
    int kt = blockIdx.x * 32, nt = blockIdx.y * 32;
    int tx = threadIdx.x & 31, ty0 = threadIdx.x >> 5;
    #pragma unroll
    for (int i = 0; i < 4; ++i) {
        int ty = ty0 + i * 8;
        int k = kt + ty;
        float v = (k < K) ? W[(size_t)k * NC + nt + tx] : 0.f;
        tile[ty][tx] = v;
    }
    __syncthreads();
    #pragma unroll
    for (int i = 0; i < 4; ++i) {
        int ty = ty0 + i * 8;
        int n = nt + ty;
        int k = kt + tx;
        float w = tile[tx][ty];
        unsigned short h = rne_bf16(w);
        th[(size_t)n * KP + k] = h;
        tl[(size_t)n * KP + k] = rne_bf16(w - bf16_to_f(h));
    }
}

// ---------------------------------------------------------------- MFMA node GEMM (pure bf16 A)
// C[M,128] = A[M,KK] @ W[KK,128]; optional dinv[row] pre-scale in epilogue (gather tables)
template <int KK, bool SCALE>
__global__ __launch_bounds__(512) void gemm_node2(const unsigned short* __restrict__ A,
                                                  const unsigned short* __restrict__ wth,
                                                  const unsigned short* __restrict__ wtl,
                                                  const float* __restrict__ dinv,
                                                  unsigned short* __restrict__ C, int M) {
    constexpr int KS = KK / 32;
    int tid = threadIdx.x;
    int lane = tid & 63, wid = tid >> 6;
    int rw = wid & 1, cg = wid >> 1;
    int l15 = lane & 15, l4 = lane >> 4;
    int cbase = cg * 32;

    FragU bh[2][KS], bl[2][KS];
    #pragma unroll
    for (int ct = 0; ct < 2; ++ct) {
        int n = cbase + ct * 16 + l15;
        #pragma unroll
        for (int ks = 0; ks < KS; ++ks) {
            int k = ks * 32 + l4 * 8;
            bh[ct][ks].s = *(const short8*)(wth + (size_t)n * KK + k);
            bl[ct][ks].s = *(const short8*)(wtl + (size_t)n * KK + k);
        }
    }

    #pragma unroll
    for (int rt = 0; rt < 2; ++rt) {
        int m0 = blockIdx.x * 64 + rt * 32 + rw * 16;
        if (m0 < M) {
            int arow = min(m0 + l15, M - 1);
            f32x4 zero = {0.f, 0.f, 0.f, 0.f};
            f32x4 acc[2] = {zero, zero};
            #pragma unroll
            for (int ks = 0; ks < KS; ++ks) {
                int k0 = ks * 32 + l4 * 8;
                FragU a;
                a.u = *(const u16x8*)(A + (size_t)arow * KK + k0);
                #pragma unroll
                for (int ct = 0; ct < 2; ++ct) {
                    acc[ct] = __builtin_amdgcn_mfma_f32_16x16x32_bf16(a.b, bh[ct][ks].b, acc[ct], 0, 0, 0);
                    acc[ct] = __builtin_amdgcn_mfma_f32_16x16x32_bf16(a.b, bl[ct][ks].b, acc[ct], 0, 0, 0);
                }
            }
            float dv0 = 1.f, dv1 = 1.f, dv2 = 1.f, dv3 = 1.f;
            if (SCALE) {
                int rbase = m0 + l4 * 4;
                dv0 = dinv[min(rbase + 0, M - 1)];
                dv1 = dinv[min(rbase + 1, M - 1)];
                dv2 = dinv[min(rbase + 2, M - 1)];
                dv3 = dinv[min(rbase + 3, M - 1)];
            }
            #pragma unroll
            for (int ct = 0; ct < 2; ++ct) {
                int col = cbase + ct * 16 + l15;
                #pragma unroll
                for (int r = 0; r < 4; ++r) {
                    int row = m0 + l4 * 4 + r;
                    if (row < M) {
                        float v = acc[ct][r];
                        if (SCALE) v *= (r == 0 ? dv0 : r == 1 ? dv1 : r == 2 ? dv2 : dv3);
                        C[(size_t)row * HC + col] = rne_bf16(v);
                    }
                }
            }
        }
    }
}

// ---------------------------------------------------------------- MFMA head GEMM, split-K
__global__ __launch_bounds__(256) void gemm_head_sk(const float* __restrict__ A,
                                                    const unsigned short* __restrict__ wth,
                                                    const unsigned short* __restrict__ wtl,
                                                    float* __restrict__ Cpart,
                                                    int M, int N, int K, int slice) {
    int tid = threadIdx.x;
    int lane = tid & 63, wid = tid >> 6;
    int rw = wid & 1, cw = wid >> 1;
    int l15 = lane & 15, l4 = lane >> 4;
    int m0 = blockIdx.y * 32 + rw * 16;
    int cb = blockIdx.x * 64 + cw * 32;
    int z = blockIdx.z;
    int kbeg = z * slice;
    int kend = min(K, kbeg + slice);
    if (m0 >= M) return;

    int arow = m0 + l15;
    f32x4 zero = {0.f, 0.f, 0.f, 0.f};
    f32x4 acc[2] = {zero, zero};

    for (int k0 = kbeg; k0 < kend; k0 += 32) {
        int ka = k0 + l4 * 8;
        const float4 p0 = *(const float4*)(A + (size_t)arow * K + ka);
        const float4 p1 = *(const float4*)(A + (size_t)arow * K + ka + 4);
        float av[8] = {p0.x, p0.y, p0.z, p0.w, p1.x, p1.y, p1.z, p1.w};
        FragU ah, al;
        #pragma unroll
        for (int i = 0; i < 8; ++i) {
            unsigned short h = rne_bf16(av[i]);
            ah.s[i] = (short)h;
            al.s[i] = (short)rne_bf16(av[i] - bf16_to_f(h));
        }
        #pragma unroll
        for (int ct = 0; ct < 2; ++ct) {
            int n = cb + ct * 16 + l15;
            FragU bh, bl;
            bh.s = *(const short8*)(wth + (size_t)n * K + ka);
            bl.s = *(const short8*)(wtl + (size_t)n * K + ka);
            acc[ct] = __builtin_amdgcn_mfma_f32_16x16x32_bf16(ah.b, bh.b, acc[ct], 0, 0, 0);
            acc[ct] = __builtin_amdgcn_mfma_f32_16x16x32_bf16(ah.b, bl.b, acc[ct], 0, 0, 0);
            acc[ct] = __builtin_amdgcn_mfma_f32_16x16x32_bf16(al.b, bh.b, acc[ct], 0, 0, 0);
        }
    }

    float* Cz = Cpart + (size_t)z * M * N;
    #pragma unroll
    for (int ct = 0; ct < 2; ++ct) {
        int col = cb + ct * 16 + l15;
        #pragma unroll
        for (int r = 0; r < 4; ++r) {
            int row = m0 + l4 * 4 + r;
            Cz[(size_t)row * N + col] = acc[ct][r];
        }
    }
}

// sum NZ partials + bias + relu; N power of two (DHID)
__global__ void k_reduce_br(const float* __restrict__ part, const float* __restrict__ bias,
                            float* __restrict__ C, int MN, int Nmask, int NZ) {
    int i = (blockIdx.x * blockDim.x + threadIdx.x) * 4;
    if (i >= MN) return;
    float4 acc = *(const float4*)(part + i);
    for (int zz = 1; zz < NZ; ++zz) {
        float4 p = *(const float4*)(part + (size_t)zz * MN + i);
        acc.x += p.x; acc.y += p.y; acc.z += p.z; acc.w += p.w;
    }
    int n = i & Nmask;
    acc.x += bias[n]; acc.y += bias[n + 1]; acc.z += bias[n + 2]; acc.w += bias[n + 3];
    acc.x = fmaxf(acc.x, 0.f); acc.y = fmaxf(acc.y, 0.f);
    acc.z = fmaxf(acc.z, 0.f); acc.w = fmaxf(acc.w, 0.f);
    *(float4*)(C + i) = acc;
}

// final [G,DH] @ [DH,3] + bout
__global__ void k_dense_out(const float* __restrict__ z, const float* __restrict__ W,
                            const float* __restrict__ b, float* __restrict__ out, int K) {
    int g = blockIdx.x;
    const float* zr = z + (size_t)g * K;
    float a0 = 0.f, a1 = 0.f, a2 = 0.f;
    for (int k = threadIdx.x; k < K; k += blockDim.x) {
        float zv = zr[k];
        a0 += zv * W[k * 3 + 0];
        a1 += zv * W[k * 3 + 1];
        a2 += zv * W[k * 3 + 2];
    }
    __shared__ float s[768];
    s[threadIdx.x] = a0; s[256 + threadIdx.x] = a1; s[512 + threadIdx.x] = a2;
    __syncthreads();
    for (int off = 128; off > 0; off >>= 1) {
        if ((int)threadIdx.x < off) {
            s[threadIdx.x]       += s[threadIdx.x + off];
            s[256 + threadIdx.x] += s[256 + threadIdx.x + off];
            s[512 + threadIdx.x] += s[512 + threadIdx.x + off];
        }
        __syncthreads();
    }
    if (threadIdx.x == 0) {
        out[g * 3 + 0] = s[0]   + b[0];
        out[g * 3 + 1] = s[256] + b[1];
        out[g * 3 + 2] = s[512] + b[2];
    }
}

// ---------------------------------------------------------------- launch
extern "C" void kernel_launch(void* const* d_in, const int* in_sizes, int n_in,
                              void* d_out, int out_size, void* d_ws, size_t ws_size,
                              hipStream_t stream) {
    const float* x         = (const float*)d_in[0];
    const float* origin    = (const float*)d_in[1];
    const float* direction = (const float*)d_in[2];
    const int*   eidx      = (const int*)d_in[3];
    const int*   batch     = (const int*)d_in[4];
    const float* W1 = (const float*)d_in[5];
    const float* W2 = (const float*)d_in[7];
    const float* W3 = (const float*)d_in[9];
    const float* g1 = (const float*)d_in[11]; const float* be1 = (const float*)d_in[12];
    const float* g2 = (const float*)d_in[13]; const float* be2 = (const float*)d_in[14];
    const float* g3 = (const float*)d_in[15]; const float* be3 = (const float*)d_in[16];
    const float* Wd0 = (const float*)d_in[17]; const float* bd0 = (const float*)d_in[18];
    const float* Wd1 = (const float*)d_in[19]; const float* bd1 = (const float*)d_in[20];
    const float* Wd2 = (const float*)d_in[21]; const float* bd2 = (const float*)d_in[22];
    const float* Wout = (const float*)d_in[23]; const float* bout = (const float*)d_in[24];
    float* out = (float*)d_out;

    const int N = in_sizes[4];
    const int E = in_sizes[3] / 2;
    const int G = in_sizes[1] / 3;
    const int* src = eidx;
    const int* dst = eidx + E;

    char* ws = (char*)d_ws;
    size_t off = 0;
    auto alloc = [&](size_t nbytes) -> void* {
        void* p = (void*)(ws + off);
        off += (nbytes + 255) & ~(size_t)255;
        return p;
    };
    // zero-init region (one memset): colstats | pooled | cntf | degcnt
    float* colstats = (float*)alloc(3 * 2 * HC * 4);
    float* pooled   = (float*)alloc((size_t)G * HC * 4);
    float* cntf     = (float*)alloc((size_t)G * 4);
    int*   degcnt   = (int*)alloc((size_t)N * 4);
    const size_t zeroBytes = 3 * 2 * HC * 4 + (size_t)G * HC * 4 + 1024 /*cntf pad*/ + (size_t)N * 4;

    float* dinv     = (float*)alloc((size_t)N * 4);
    int*   part     = (int*)alloc((size_t)N * 4);
    int*   bsum     = (int*)alloc(256 * 4);
    int*   row_start= (int*)alloc((size_t)N * 4);
    int*   rank     = (int*)alloc((size_t)E * 4);
    int*   csr      = (int*)alloc((size_t)E * 4);
    unsigned short* xb   = (unsigned short*)alloc((size_t)N * FIN * 2);
    unsigned short* aggx = (unsigned short*)alloc((size_t)N * FIN * 2);
    unsigned short* tabA = (unsigned short*)alloc((size_t)N * HC * 2);
    unsigned short* tabB = (unsigned short*)alloc((size_t)N * HC * 2);
    unsigned short* wt1h = (unsigned short*)alloc((size_t)FIN * HC * 2);
    unsigned short* wt1l = (unsigned short*)alloc((size_t)FIN * HC * 2);
    unsigned short* wt2h = (unsigned short*)alloc((size_t)HC * HC * 2);
    unsigned short* wt2l = (unsigned short*)alloc((size_t)HC * HC * 2);
    unsigned short* wt3h = (unsigned short*)alloc((size_t)HC * HC * 2);
    unsigned short* wt3l = (unsigned short*)alloc((size_t)HC * HC * 2);
    unsigned short* wd0h = (unsigned short*)alloc((size_t)DHID * ZKP * 2);
    unsigned short* wd0l = (unsigned short*)alloc((size_t)DHID * ZKP * 2);
    unsigned short* wd1h = (unsigned short*)alloc((size_t)DHID * DHID * 2);
    unsigned short* wd1l = (unsigned short*)alloc((size_t)DHID * DHID * 2);
    unsigned short* wd2h = (unsigned short*)alloc((size_t)DHID * DHID * 2);
    unsigned short* wd2l = (unsigned short*)alloc((size_t)DHID * DHID * 2);
    float* zbuf     = (float*)alloc((size_t)G * ZKP * 4);
    float* t0       = (float*)alloc((size_t)G * DHID * 4);
    float* t1       = (float*)alloc((size_t)G * DHID * 4);
    float* kpart    = (float*)alloc((size_t)8 * G * DHID * 4);   // 8 MB split-K partials
    (void)ws_size;

    const int nScanBlk = (N + 255) / 256;
    const int gemmBlk = (N + 63) / 64;
    const int gatherBlk = (N + 15) / 16;
    const int total8 = N * HC / 8;
    const float invN = 1.0f / (float)N;

    hipMemsetAsync(colstats, 0, zeroBytes, stream);

    // ---- weight prep ----
    k_wprep_all<<<(FIN * HC + 2 * HC * HC + 255) / 256, 256, 0, stream>>>(
        W1, W2, W3, wt1h, wt1l, wt2h, wt2l, wt3h, wt3l);
    k_wprep2<<<dim3(ZKP / 32, DHID / 32), 256, 0, stream>>>(Wd0, wd0h, wd0l, ZK, ZKP, DHID);
    k_wprep2<<<dim3(DHID / 32, DHID / 32), 256, 0, stream>>>(Wd1, wd1h, wd1l, DHID, DHID, DHID);
    k_wprep2<<<dim3(DHID / 32, DHID / 32), 256, 0, stream>>>(Wd2, wd2h, wd2l, DHID, DHID, DHID);

    // ---- CSR build (atomic-free scatter via rank) ----
    k_deg_rank<<<(E + 255) / 256, 256, 0, stream>>>(dst, degcnt, rank, E);
    k_scan1<<<nScanBlk, 256, 0, stream>>>(degcnt, part, bsum, dinv, N);
    k_scan2<<<1, 256, 0, stream>>>(bsum, nScanBlk);
    k_scan3<<<nScanBlk, 256, 0, stream>>>(part, bsum, row_start, N);
    k_scatter3<<<(E + 255) / 256, 256, 0, stream>>>(src, dst, rank, row_start, csr, E);

    // x -> bf16, pre-scaled by dinv (needs dinv => after scan1)
    k_xtobf<<<(N * FIN / 4 + 255) / 256, 256, 0, stream>>>(x, dinv, xb, N * FIN / 4);

    // ---- layer 1: gather(x') -> gemm -> stats0 ----
    k_gather3<FIN><<<gatherBlk, 256, 0, stream>>>(xb, csr, row_start, degcnt, dinv, aggx, N);
    gemm_node2<FIN, false><<<gemmBlk, 512, 0, stream>>>(aggx, wt1h, wt1l, nullptr, tabA, N);
    k_bn_reduce3<<<256, 256, 0, stream>>>(tabA, colstats + 0 * 2 * HC, N);

    // ---- layer 2: BN1 apply -> gemm(scale dinv) -> gather -> stats1 ----
    k_bn_apply3<<<(total8 + 255) / 256, 256, 0, stream>>>(tabA, colstats + 0 * 2 * HC,
                                                          g1, be1, invN, total8);
    gemm_node2<HC, true><<<gemmBlk, 512, 0, stream>>>(tabA, wt2h, wt2l, dinv, tabB, N);
    k_gather3<HC><<<gatherBlk, 256, 0, stream>>>(tabB, csr, row_start, degcnt, dinv, tabA, N);
    k_bn_reduce3<<<256, 256, 0, stream>>>(tabA, colstats + 1 * 2 * HC, N);

    // ---- layer 3 ----
    k_bn_apply3<<<(total8 + 255) / 256, 256, 0, stream>>>(tabA, colstats + 1 * 2 * HC,
                                                          g2, be2, invN, total8);
    gemm_node2<HC, true><<<gemmBlk, 512, 0, stream>>>(tabA, wt3h, wt3l, dinv, tabB, N);
    k_gather3<HC><<<gatherBlk, 256, 0, stream>>>(tabB, csr, row_start, degcnt, dinv, tabA, N);
    k_bn_reduce3<<<256, 256, 0, stream>>>(tabA, colstats + 2 * 2 * HC, N);

    // ---- pool (BN3 inline) + z ----
    k_pool<<<512, HC, 0, stream>>>(tabA, batch, colstats + 2 * 2 * HC, g3, be3, invN,
                                   pooled, cntf, N);
    k_build_z<<<G, 192, 0, stream>>>(pooled, cntf, origin, direction, zbuf, G);

    // ---- dense head: split-K MFMA + reduce ----
    const int MN = G * DHID;
    const int rblk = (MN / 4 + 255) / 256;

    gemm_head_sk<<<dim3(DHID / 64, (G + 31) / 32, 5), 256, 0, stream>>>(
        zbuf, wd0h, wd0l, kpart, G, DHID, ZKP, 32);
    k_reduce_br<<<rblk, 256, 0, stream>>>(kpart, bd0, t0, MN, DHID - 1, 5);

    gemm_head_sk<<<dim3(DHID / 64, (G + 31) / 32, 8), 256, 0, stream>>>(
        t0, wd1h, wd1l, kpart, G, DHID, DHID, 128);
    k_reduce_br<<<rblk, 256, 0, stream>>>(kpart, bd1, t1, MN, DHID - 1, 8);

    gemm_head_sk<<<dim3(DHID / 64, (G + 31) / 32, 8), 256, 0, stream>>>(
        t1, wd2h, wd2l, kpart, G, DHID, DHID, 128);
    k_reduce_br<<<rblk, 256, 0, stream>>>(kpart, bd2, t0, MN, DHID - 1, 8);

    k_dense_out<<<G, 256, 0, stream>>>(t0, Wout, bout, out, DHID);
}